// Round 4
// baseline (262.462 us; speedup 1.0000x reference)
//
#include <hip/hip_runtime.h>
#include <hip/hip_bf16.h>
#include <math.h>

#define NB 16
#define NC 64
#define NH 160
#define NW 160

typedef __attribute__((ext_vector_type(8))) short bf16x8;
typedef __attribute__((ext_vector_type(4))) float f32x4;
typedef __attribute__((ext_vector_type(8))) unsigned short u16x8;
typedef __attribute__((ext_vector_type(4))) unsigned short u16x4;

__device__ __forceinline__ unsigned short f2bf(float v) {
  union { __hip_bfloat16 b; unsigned short u; } cv; cv.b = __float2bfloat16(v); return cv.u;
}
__device__ __forceinline__ float bf2f(unsigned short u) {
  union { unsigned u; float f; } cv; cv.u = ((unsigned)u) << 16; return cv.f;
}

// ---------------------------------------------------------------------------
// Pack both conv weights (OIHW fp32) -> A-fragment order for mfma 16x16x32:
// apk[((ct*18 + ks)*64 + lane)*8 + j];  ks=(kh*3+kw)*2+cih
// co = ct*16 + (lane&15); ci = cih*32 + (lane>>4)*8 + j
// ---------------------------------------------------------------------------
__global__ void pack_w_kernel2(const float* __restrict__ wA, const float* __restrict__ wB,
                               unsigned short* __restrict__ apkA, unsigned short* __restrict__ apkB) {
  int idx = blockIdx.x * 256 + threadIdx.x;
  if (idx >= 2 * 36864) return;
  const float* w = (idx < 36864) ? wA : wB;
  unsigned short* apk = (idx < 36864) ? apkA : apkB;
  int i = (idx < 36864) ? idx : idx - 36864;
  int j = i & 7, l = (i >> 3) & 63, rest = i >> 9;
  int ks = rest % 18, ct = rest / 18;
  int cih = ks & 1, tap = ks >> 1, kh = tap / 3, kw = tap % 3;
  int co = ct * 16 + (l & 15), ci = cih * 32 + (l >> 4) * 8 + j;
  apk[i + (idx < 36864 ? 0 : 0)] = f2bf(w[(((size_t)co * NC + ci) * 3 + kh) * 3 + kw]);
}

// x NCHW f32 -> xt NHWC bf16. Block = (b,h).
__global__ __launch_bounds__(256) void to_nhwc(const float* __restrict__ x,
                                               unsigned short* __restrict__ xt) {
  __shared__ unsigned short l[64 * 162];
  int bh = blockIdx.x; int b = bh / NH, h = bh % NH;
  for (int i = threadIdx.x; i < 64 * NW; i += 256) {
    int ci = i / NW, w = i % NW;
    l[ci * 162 + w] = f2bf(x[(((size_t)b * NC + ci) * NH + h) * NW + w]);
  }
  __syncthreads();
  unsigned short* o = xt + ((size_t)b * NH + h) * NW * NC;
  for (int i = threadIdx.x; i < NW * 8; i += 256) {
    int w = i >> 3, s = i & 7;
    u16x8 v;
#pragma unroll
    for (int j = 0; j < 8; ++j) v[j] = l[(s * 8 + j) * 162 + w];
    *(u16x8*)&o[w * 64 + s * 8] = v;
  }
}

// ---------------------------------------------------------------------------
// Sliding-row implicit-GEMM conv3x3 (SAME) via MFMA 16x16x32 bf16.
// Block = (b, 10-h strip, 32-w slice). 256 thr = 4 waves; wave = ct (16 co).
// Ring: 4 row slots [34 wc][64 ci] bf16 (17.4 KB), XOR-swizzled granules.
// Weights in registers (18 frags/wave). Grid 1280 -> 5 blocks/CU, 20 waves/CU.
// ---------------------------------------------------------------------------
template<bool FINAL>
__global__ __launch_bounds__(256, 4) void conv3x3_mfma3(
    const unsigned short* __restrict__ in_nhwc, const unsigned short* __restrict__ apk,
    const float* __restrict__ gg, const float* __restrict__ bbeta,
    const float* __restrict__ mmean, const float* __restrict__ vvar,
    void* __restrict__ outv, const float* __restrict__ scores,
    const float* __restrict__ xres)
{
  __shared__ unsigned short ring[4 * 34 * 64];   // 17,408 B

  const int t = threadIdx.x, lane = t & 63, wave = t >> 6;
  const int q = lane >> 4, col = lane & 15;

  int g = blockIdx.x;                    // 1280 = 8 * 160, bijective XCD swizzle
  int sw = (g & 7) * 160 + (g >> 3);
  const int b = sw / 80;
  int rem = sw % 80;
  const int h0 = (rem / 5) * 10, w0 = (rem % 5) * 32;

  // per-thread BN/score params (co = wave*16 + q*4 + r)
  float scR[4], shR[4], scoR[4];
#pragma unroll
  for (int r = 0; r < 4; ++r) {
    int co = wave * 16 + q * 4 + r;
    float s = gg[co] * rsqrtf(vvar[co] + 1e-5f);
    scR[r] = s; shR[r] = bbeta[co] - mmean[co] * s;
    scoR[r] = FINAL ? scores[b * NC + co] : 0.f;
  }

  // weights -> registers, once
  bf16x8 wf[18];
#pragma unroll
  for (int ks = 0; ks < 18; ++ks)
    wf[ks] = *(const bf16x8*)&apk[((size_t)(wave * 18 + ks) * 64 + lane) * 8];

  const unsigned short* inb = in_nhwc + (size_t)b * NH * NW * 64;

  // staging: 34 wc x 8 granules = 272 chunks; thread t -> chunk t, and t<16 -> 256+t
#define STG_ISSUE(ROW)                                                        \
  int row = (ROW);                                                            \
  bool rowok = (unsigned)row < (unsigned)NH;                                  \
  int rowc = row < 0 ? 0 : (row > NH - 1 ? NH - 1 : row);                     \
  int slot = (row & 3) * 2176;                                                \
  u16x8 v0 = {}, v1 = {}; int a0, a1 = 0;                                     \
  { int wcc = t >> 3, s8 = t & 7; int wsrc = w0 + wcc - 1;                    \
    a0 = slot + wcc * 64 + ((s8 ^ (wcc & 7)) << 3);                           \
    if (rowok && (unsigned)wsrc < (unsigned)NW)                               \
      v0 = *(const u16x8*)&inb[((size_t)rowc * NW + wsrc) * 64 + s8 * 8]; }   \
  if (t < 16) { int c = 256 + t; int wcc = c >> 3, s8 = c & 7;                \
    int wsrc = w0 + wcc - 1;                                                  \
    a1 = slot + wcc * 64 + ((s8 ^ (wcc & 7)) << 3);                           \
    if (rowok && (unsigned)wsrc < (unsigned)NW)                               \
      v1 = *(const u16x8*)&inb[((size_t)rowc * NW + wsrc) * 64 + s8 * 8]; }
#define STG_COMMIT()                                                          \
  *(u16x8*)&ring[a0] = v0;                                                    \
  if (t < 16) *(u16x8*)&ring[a1] = v1;

  // prologue: rows h0-1 .. h0+1
  for (int rr = 0; rr < 3; ++rr) {
    STG_ISSUE(h0 - 1 + rr)
    STG_COMMIT()
  }
  __syncthreads();

  for (int h = h0; h < h0 + 10; ++h) {
    // phase 1: issue global loads for row h+2 (async-stage split)
    STG_ISSUE(h + 2)

    // phase 2: compute (ring rows h-1..h+1)
    int rbs[3] = { ((h - 1) & 3) * 2176, (h & 3) * 2176, ((h + 1) & 3) * 2176 };
    f32x4 acc[2];
    acc[0] = (f32x4){0.f, 0.f, 0.f, 0.f};
    acc[1] = (f32x4){0.f, 0.f, 0.f, 0.f};
#pragma unroll
    for (int kh = 0; kh < 3; ++kh) {
#pragma unroll
      for (int kw = 0; kw < 3; ++kw) {
#pragma unroll
        for (int cih = 0; cih < 2; ++cih) {
          const int ks = (kh * 3 + kw) * 2 + cih;
          int wcb = col + kw;
          int ea = rbs[kh] + wcb * 64 + (((cih << 2) + q) ^ (wcb & 7)) * 8;
          const bf16x8* bp = (const bf16x8*)&ring[ea];
          acc[0] = __builtin_amdgcn_mfma_f32_16x16x32_bf16(wf[ks], bp[0],   acc[0], 0, 0, 0);
          acc[1] = __builtin_amdgcn_mfma_f32_16x16x32_bf16(wf[ks], bp[128], acc[1], 0, 0, 0);
        }
      }
    }

    // phase 3: commit staged row to ring (vmcnt hidden under compute)
    STG_COMMIT()

    if constexpr (!FINAL) {
      __shared__ unsigned short epi[32 * 72];    // 4,608 B
      // epilogue: silu(bn1(acc)) -> epi transpose -> y NHWC
#pragma unroll
      for (int wt = 0; wt < 2; ++wt) {
        u16x4 ev;
#pragma unroll
        for (int r = 0; r < 4; ++r) {
          float z = scR[r] * acc[wt][r] + shR[r];
          ev[r] = f2bf(z / (1.f + __expf(-z)));
        }
        *(u16x4*)&epi[(wt * 16 + col) * 72 + wave * 16 + q * 4] = ev;
      }
      __syncthreads();
      unsigned short* yo = (unsigned short*)outv + (((size_t)b * NH + h) * NW + w0) * 64;
      { int w = t >> 3, s = t & 7;
        *(u16x8*)&yo[w * 64 + s * 8] = *(const u16x8*)&epi[w * 72 + s * 8]; }
      __syncthreads();
    } else {
      // final: out = x + relu(bn2(score*conv + y)); y read from ring (row h)
      float* outp = (float*)outv;
      int rb1 = (h & 3) * 2176;
#pragma unroll
      for (int wt = 0; wt < 2; ++wt) {
        int wcc = wt * 16 + col + 1;
        int gr = (wave * 2 + (q >> 1)) ^ (wcc & 7);
        u16x4 yv = *(const u16x4*)&ring[rb1 + wcc * 64 + gr * 8 + (q & 1) * 4];
#pragma unroll
        for (int r = 0; r < 4; ++r) {
          int co = wave * 16 + q * 4 + r;
          float rv = scoR[r] * acc[wt][r] + bf2f(yv[r]);
          float rb_ = scR[r] * rv + shR[r];
          rb_ = fmaxf(rb_, 0.f);
          size_t oi = (((size_t)b * NC + co) * NH + h) * NW + w0 + wt * 16 + col;
          outp[oi] = xres[oi] + rb_;
        }
      }
      __syncthreads();
    }
  }
#undef STG_ISSUE
#undef STG_COMMIT
}

// ycol[b][w][c] = sum_h y_nhwc[b][h][w][c]
__global__ void colsum_kernel(const unsigned short* __restrict__ y, float* __restrict__ ycol) {
  int id = blockIdx.x * 256 + threadIdx.x;
  if (id >= NB * NW * NC) return;
  int c = id & 63, bw = id >> 6;
  int w = bw % NW, b = bw / NW;
  float s = 0.f;
  for (int h = 0; h < NH; ++h)
    s += bf2f(y[(((size_t)b * NH + h) * NW + w) * 64 + c]);
  ycol[id] = s;
}

// one block per b; wksum computed in-block.
__global__ __launch_bounds__(256, 1) void scores_kernel(
    const unsigned short* __restrict__ y, const float* __restrict__ ycol,
    const float* __restrict__ wk, const float* __restrict__ wq,
    float* __restrict__ scores)
{
  __shared__ float Z[NC * 3 * 162];
  __shared__ float wksL[576];
  __shared__ float ks[NW];
  __shared__ float U[576];
  const int b = blockIdx.x, t = threadIdx.x;

  for (int o = t; o < 576; o += 256) {
    float s = 0.f;
    for (int j = 0; j < NC; ++j) s += wk[(size_t)j * 576 + o];
    wksL[o] = s;
  }
  for (int idx = t; idx < NC * 3 * 162; idx += 256) {
    int lw = idx % 162;
    int kh = (idx / 162) % 3;
    int i  = idx / (162 * 3);
    int w = lw - 1;
    float val = 0.f;
    if ((unsigned)w < (unsigned)NW) {
      val = ycol[((size_t)b * NW + w) * 64 + i];
      if (kh == 0) val -= bf2f(y[(((size_t)b * NH + (NH - 1)) * NW + w) * 64 + i]);
      if (kh == 2) val -= bf2f(y[(((size_t)b * NH) * NW + w) * 64 + i]);
    }
    Z[idx] = val;
  }
  __syncthreads();

  if (t < NW) {
    float s = 0.f;
    for (int ik = 0; ik < NC * 3; ++ik) {
      const float* zr = &Z[ik * 162 + t];
      const float* wp = &wksL[ik * 3];
      s += wp[0] * zr[0] + wp[1] * zr[1] + wp[2] * zr[2];
    }
    ks[t] = s;
  }
  __syncthreads();

  for (int o = t; o < 576; o += 256) {
    int kw = o % 3; int ik = o / 3;
    const float* zr = &Z[ik * 162 + kw];
    float s = 0.f;
    for (int w = 0; w < NW; ++w) s += zr[w] * ks[w];
    U[o] = s;
  }
  __syncthreads();

  if (t < NC) {
    const float* wp = wq + (size_t)t * 576;
    float s = 0.f;
    for (int o = 0; o < 576; ++o) s += wp[o] * U[o];
    const float scale = 1.0f / (sqrtf((float)NW) * (float)NH * (float)NH);
    float f = s * scale;
    float mx = f;
#pragma unroll
    for (int off = 32; off; off >>= 1) mx = fmaxf(mx, __shfl_xor(mx, off));
    float e = __expf(f - mx);
    float sm = e;
#pragma unroll
    for (int off = 32; off; off >>= 1) sm += __shfl_xor(sm, off);
    scores[b * NC + t] = e / sm;
  }
}

extern "C" void kernel_launch(void* const* d_in, const int* in_sizes, int n_in,
                              void* d_out, int out_size, void* d_ws, size_t ws_size,
                              hipStream_t stream) {
  const float* x  = (const float*)d_in[0];
  const float* w1 = (const float*)d_in[1];
  const float* g1 = (const float*)d_in[2];
  const float* b1 = (const float*)d_in[3];
  const float* m1 = (const float*)d_in[4];
  const float* v1 = (const float*)d_in[5];
  const float* wq = (const float*)d_in[6];
  const float* wk = (const float*)d_in[7];
  const float* wv = (const float*)d_in[8];
  const float* g2 = (const float*)d_in[9];
  const float* b2 = (const float*)d_in[10];
  const float* m2 = (const float*)d_in[11];
  const float* v2 = (const float*)d_in[12];
  float* out = (float*)d_out;

  // ws: apk1 | apk2 | ycol | scr | xt(NHWC bf16) | y(NHWC bf16)
  unsigned short* apk1 = (unsigned short*)d_ws;
  unsigned short* apk2 = apk1 + 36864;
  float* ycol = (float*)(apk2 + 36864);
  float* scr  = ycol + NB * NW * NC;
  unsigned short* xt = (unsigned short*)(scr + 1024);
  unsigned short* y  = xt + (size_t)NB * NH * NW * 64;

  pack_w_kernel2<<<dim3(288), 256, 0, stream>>>(w1, wv, apk1, apk2);
  to_nhwc<<<dim3(NB * NH), 256, 0, stream>>>(x, xt);

  conv3x3_mfma3<false><<<dim3(1280), 256, 0, stream>>>(
      xt, apk1, g1, b1, m1, v1, (void*)y, nullptr, nullptr);

  colsum_kernel<<<dim3((NB * NW * NC + 255) / 256), 256, 0, stream>>>(y, ycol);
  scores_kernel<<<dim3(NB), 256, 0, stream>>>(y, ycol, wk, wq, scr);

  conv3x3_mfma3<true><<<dim3(1280), 256, 0, stream>>>(
      y, apk2, g2, b2, m2, v2, (void*)out, scr, x);
}